// Round 19
// baseline (138.012 us; speedup 1.0000x reference)
//
#include <hip/hip_runtime.h>
#include <hip/hip_bf16.h>

typedef __attribute__((ext_vector_type(8))) short short8;
typedef __attribute__((ext_vector_type(4))) float f32x4;
typedef __attribute__((ext_vector_type(4))) float fv4;
typedef __attribute__((ext_vector_type(4))) unsigned int u32x4;

#define MFMA16(a, b, c) __builtin_amdgcn_mfma_f32_16x16x32_bf16((a), (b), (c), 0, 0, 0)
#define SBAR() __builtin_amdgcn_sched_barrier(0)
#define RBAR() __builtin_amdgcn_s_barrier()

typedef const __attribute__((address_space(1))) unsigned int gu32;
typedef __attribute__((address_space(3))) unsigned int lu32;

// float -> bf16 RNE (inputs are finite; no NaN handling needed)
__device__ __forceinline__ short f2b(float f) {
  unsigned int x = __builtin_bit_cast(unsigned int, f);
  x += 0x7fffu + ((x >> 16) & 1u);
  return (short)(x >> 16);
}

// packed f32x2 -> bf16x2 (RNE); D.lo = S0, D.hi = S1
__device__ __forceinline__ unsigned int cvtpk(float lo, float hi) {
  unsigned int r;
  asm("v_cvt_pk_bf16_f32 %0, %1, %2" : "=v"(r) : "v"(lo), "v"(hi));
  return r;
}

// hardware 2^x as a compiler-known instruction (TRANS hazards handled)
#define hexp2(x) __builtin_amdgcn_exp2f(x)

// ===================== weight prep =====================
// BTall = [WqT|WkT|WvT] contiguous [1536][1024] bf16; Wq pre-scaled by
// d_model^-0.5 * log2(e). WoT: [1024][512] bf16.
__global__ void prep_weights(const float* __restrict__ Wq, const float* __restrict__ Wk,
                             const float* __restrict__ Wv, const float* __restrict__ Wo,
                             short* __restrict__ WqT, short* __restrict__ WkT,
                             short* __restrict__ WvT, short* __restrict__ WoT) {
  const float SC2 = 0.045084220027780106f;  // (1/32) * log2(e)
  int idx = blockIdx.x * 256 + threadIdx.x;
  if (idx < 3 * 512 * 1024) {
    int wsel = idx >> 19;
    int rem = idx & ((1 << 19) - 1);
    int n = rem >> 10;
    int d = rem & 1023;
    const float* W = (wsel == 0) ? Wq : ((wsel == 1) ? Wk : Wv);
    short* WT = (wsel == 0) ? WqT : ((wsel == 1) ? WkT : WvT);
    float v = W[(n >> 5) * (1024 * 32) + d * 32 + (n & 31)];
    if (wsel == 0) v *= SC2;
    WT[n * 1024 + d] = f2b(v);
  } else {
    int idx2 = idx - 3 * 512 * 1024;
    int n = idx2 >> 9;
    int kk = idx2 & 511;
    WoT[n * 512 + kk] = f2b(Wo[kk * 1024 + n]);
  }
}

// ===================== projection GEMM (16-wave max-occupancy) =====================
// R18 post-mortem: 8 structural nulls; surviving hypothesis is chip-wide
// memory-level parallelism — every proj variant ran 16 waves/CU (VGPR>64)
// and plateaued at ~1TB/s effective HBM, while prep_weights at 32 blocks/CU
// streams ~3TB/s. This round: 1024-thread 16-wave blocks, per-wave acc[2][2]
// (16 VGPR, est. live ~50), launch_bounds(1024,8) caps VGPR at 64 ->
// 2 blocks/CU x 16 waves = 32 waves/CU (occupancy cap). Tile 128x128, BK=32,
// 24KB single buffer, 2 barriers/step. Staging: every wave 1 A-chunk
// (8 rows x 128B), waves 8..15 also 1 B-chunk (16 rows x 64B); all address/
// swizzle formulas byte-identical to R13/R18 (absmax-verified):
// A slot^=(row&7) of 8, B slot^=((row>>1)&3) of 4, same XOR at read;
// cvtpk f32->bf16 at A-fragment read. Grid 768 = 64bm x 12bn (q/k/v fused),
// id%8==bm%8 XCD-pins A panels.
__global__ __launch_bounds__(1024, 8) void proj_gemm(
    const float* __restrict__ q, const float* __restrict__ k, const float* __restrict__ v,
    const short* __restrict__ BTall,
    short* __restrict__ Qb, short* __restrict__ Kb, short* __restrict__ Vtb) {
  __shared__ char smem[24576];  // A f32 [128][32] @0 (16KB) + B bf16 [128][32] @16384 (8KB)
  const int tid = threadIdx.x;
  const int lane = tid & 63;
  const int w = tid >> 6;          // 0..15
  const int l15 = lane & 15, g = lane >> 4;
  const int mw = (w & 3) * 32;     // 4 m-waves x 32 rows
  const int nw = (w >> 2) * 32;    // 4 n-waves x 32 cols
  const int id = blockIdx.x;
  const int bm = id & 63;
  const int bn = id >> 6;          // 0..11
  const int zz = bn >> 2;          // 0:q 1:k 2:v
  const int bnz = bn & 3;
  const float* Az = (zz == 0) ? q : ((zz == 1) ? k : v);
  const short* BT = BTall + (size_t)zz * 512 * 1024;
  const int bm0 = bm * 128, bn0z = bnz * 128;

  // A staging: chunk w = rows 8w+(lane>>3), slot au=lane&7 (16B of 8)
  const int ar = lane >> 3;
  const int au = lane & 7;
  // B staging (waves 8..15): chunk w-8 = rows 16(w-8)+(lane>>2), slot bu=lane&3
  const int br = lane >> 2;
  const int bu = lane & 3;

  f32x4 zf = {0.f, 0.f, 0.f, 0.f};
  f32x4 acc[2][2];
#pragma unroll
  for (int a = 0; a < 2; ++a)
#pragma unroll
    for (int bq = 0; bq < 2; ++bq) acc[a][bq] = zf;

  for (int k0 = 0; k0 < 1024; k0 += 32) {
    // ---- stage (prev compute finished at loop-tail barrier) ----
    {
      int rowa = 8 * w + ar;
      __builtin_amdgcn_global_load_lds(
          (gu32*)(Az + (size_t)(bm0 + rowa) * 1024 + k0 + 4 * (au ^ (rowa & 7))),
          (lu32*)(smem + w * 1024), 16, 0, 0);
    }
    if (w >= 8) {  // wave-uniform branch
      int rowb = 16 * (w - 8) + br;
      __builtin_amdgcn_global_load_lds(
          (gu32*)(BT + (size_t)(bn0z + rowb) * 1024 + k0 +
                  8 * (bu ^ ((rowb >> 1) & 3))),
          (lu32*)(smem + 16384 + (w - 8) * 1024), 16, 0, 0);
    }
    __syncthreads();  // drains vmcnt: tile ready (32 waves/CU hide the drain)

    {
      short8 bfr[2];
#pragma unroll
      for (int nf = 0; nf < 2; ++nf) {
        int row = nw + nf * 16 + l15;
        bfr[nf] = *(const short8*)(smem + 16384 + row * 64 +
                                   ((g ^ ((row >> 1) & 3)) * 16));
      }
#pragma unroll
      for (int mf = 0; mf < 2; ++mf) {
        int row = mw + mf * 16 + l15;
        fv4 a0 = *(const fv4*)(smem + row * 128 + (((2 * g) ^ (row & 7)) * 16));
        fv4 a1 = *(const fv4*)(smem + row * 128 + (((2 * g + 1) ^ (row & 7)) * 16));
        u32x4 wv;
        wv[0] = cvtpk(a0[0], a0[1]);
        wv[1] = cvtpk(a0[2], a0[3]);
        wv[2] = cvtpk(a1[0], a1[1]);
        wv[3] = cvtpk(a1[2], a1[3]);
        short8 af = __builtin_bit_cast(short8, wv);
        acc[mf][0] = MFMA16(af, bfr[0], acc[mf][0]);
        acc[mf][1] = MFMA16(af, bfr[1], acc[mf][1]);
      }
    }
    __syncthreads();  // compute done before next stage overwrites
  }

#pragma unroll
  for (int mf = 0; mf < 2; ++mf)
#pragma unroll
    for (int nf = 0; nf < 2; ++nf)
#pragma unroll
      for (int i = 0; i < 4; ++i) {
        int row = bm0 + mw + mf * 16 + g * 4 + i;  // m index (b*2048+s)
        int col = bn0z + nw + nf * 16 + l15;       // n within this input's 512
        int bb = row >> 11, ss = row & 2047;
        int hh = col >> 5, ee = col & 31;
        short val = f2b(acc[mf][nf][i]);
        if (zz == 2)
          Vtb[((size_t)(bb * 16 + hh) * 32 + ee) * 2048 + ss] = val;
        else if (zz == 1)
          Kb[((size_t)(bb * 16 + hh) * 2048 + ss) * 32 + ee] = val;
        else
          Qb[((size_t)(bb * 16 + hh) * 2048 + ss) * 32 + ee] = val;
      }
}

// ===================== output GEMM (T4 2-buf counted vmcnt, unchanged from R13) =====================
__global__ __launch_bounds__(256, 2) void out_gemm(const short* __restrict__ X,
                                                   const short* __restrict__ WoT,
                                                   float* __restrict__ out) {
  __shared__ char smem[32768];
  const int tid = threadIdx.x;
  const int lane = tid & 63;
  const int w = tid >> 6;
  const int l15 = lane & 15, g = lane >> 4;
  const int wm = (w >> 1) * 64, wn = (w & 1) * 64;
  const int id = blockIdx.x;
  const int bm0 = (id & 63) * 128, bn0 = (id >> 6) * 128;

  const int br = (lane >> 2);
  const int bu = lane & 3;

  f32x4 zf = {0.f, 0.f, 0.f, 0.f};
  f32x4 acc[4][4];
#pragma unroll
  for (int a = 0; a < 4; ++a)
#pragma unroll
    for (int bq = 0; bq < 4; ++bq) acc[a][bq] = zf;

#define STAGE(base, k0)                                                        \
  {                                                                            \
    _Pragma("unroll") for (int i = 0; i < 2; ++i) {                            \
      int row = 32 * w + 16 * i + br;                                          \
      __builtin_amdgcn_global_load_lds(                                        \
          (gu32*)(X + (size_t)(bm0 + row) * 512 + (k0) +                       \
                  8 * (bu ^ ((row >> 1) & 3))),                                \
          (lu32*)(smem + (base) + w * 2048 + i * 1024), 16, 0, 0);             \
      __builtin_amdgcn_global_load_lds(                                        \
          (gu32*)(WoT + (size_t)(bn0 + row) * 512 + (k0) +                     \
                  8 * (bu ^ ((row >> 1) & 3))),                                \
          (lu32*)(smem + (base) + 8192 + w * 2048 + i * 1024), 16, 0, 0);      \
    }                                                                          \
  }

#define COMPUTE(base)                                                          \
  {                                                                            \
    short8 af[4], bfr[4];                                                      \
    _Pragma("unroll") for (int mf = 0; mf < 4; ++mf) {                         \
      int row = wm + mf * 16 + l15;                                            \
      af[mf] = *(const short8*)(smem + (base) + row * 64 +                     \
                                ((g ^ ((row >> 1) & 3)) * 16));                \
    }                                                                          \
    _Pragma("unroll") for (int nf = 0; nf < 4; ++nf) {                         \
      int row = wn + nf * 16 + l15;                                            \
      bfr[nf] = *(const short8*)(smem + (base) + 8192 + row * 64 +             \
                                 ((g ^ ((row >> 1) & 3)) * 16));               \
    }                                                                          \
    __builtin_amdgcn_s_setprio(1);                                             \
    _Pragma("unroll") for (int mf = 0; mf < 4; ++mf)                           \
        _Pragma("unroll") for (int nf = 0; nf < 4; ++nf)                       \
            acc[mf][nf] = MFMA16(af[mf], bfr[nf], acc[mf][nf]);                \
    __builtin_amdgcn_s_setprio(0);                                             \
  }

  STAGE(0, 0);
  for (int k0 = 0; k0 < 512; k0 += 32) {
    const int cur = (k0 >> 5) & 1;
    const int cbase = cur * 16384;
    const int nbase = (cur ^ 1) * 16384;
    if (k0 + 32 < 512) {
      STAGE(nbase, k0 + 32);
      asm volatile("s_waitcnt vmcnt(4)" ::: "memory");
    } else {
      asm volatile("s_waitcnt vmcnt(0)" ::: "memory");
    }
    RBAR();
    SBAR();
    COMPUTE(cbase);
    RBAR();
  }
#undef STAGE
#undef COMPUTE

#pragma unroll
  for (int mf = 0; mf < 4; ++mf)
#pragma unroll
    for (int nf = 0; nf < 4; ++nf)
#pragma unroll
      for (int i = 0; i < 4; ++i) {
        int row = bm0 + wm + mf * 16 + g * 4 + i;
        int col = bn0 + wn + nf * 16 + l15;
        out[(size_t)row * 1024 + col] = acc[mf][nf][i];
      }
}

// ===================== fused flash attention (unchanged from R9) =====================
__device__ __forceinline__ void qk_half(short8 k0, short8 k1, short8 k2, short8 k3,
                                        short8 qf, const f32x4& zf,
                                        short8& pf0, short8& pf1) {
  f32x4 s0 = MFMA16(k0, qf, zf);
  f32x4 s1 = MFMA16(k1, qf, zf);
  f32x4 s2 = MFMA16(k2, qf, zf);
  f32x4 s3 = MFMA16(k3, qf, zf);
#pragma unroll
  for (int i = 0; i < 4; ++i) {
    s0[i] = hexp2(s0[i]);
    s1[i] = hexp2(s1[i]);
    s2[i] = hexp2(s2[i]);
    s3[i] = hexp2(s3[i]);
  }
  u32x4 w0, w1;
  w0[0] = cvtpk(s0[0], s0[1]);
  w0[1] = cvtpk(s0[2], s0[3]);
  w0[2] = cvtpk(s1[0], s1[1]);
  w0[3] = cvtpk(s1[2], s1[3]);
  w1[0] = cvtpk(s2[0], s2[1]);
  w1[1] = cvtpk(s2[2], s2[3]);
  w1[2] = cvtpk(s3[0], s3[1]);
  w1[3] = cvtpk(s3[2], s3[3]);
  pf0 = __builtin_bit_cast(short8, w0);
  pf1 = __builtin_bit_cast(short8, w1);
}

__global__ __launch_bounds__(256, 4) void attn(const short* __restrict__ Qb,
                                               const short* __restrict__ Kb,
                                               const short* __restrict__ Vtb,
                                               short* __restrict__ X) {
  __shared__ short KV[2][2][2048];
  const int tid = threadIdx.x;
  const int lane = tid & 63;
  const int w = tid >> 6;
  const int l15 = lane & 15, g = lane >> 4;
  const int id = blockIdx.x;
  const int bh = id & 63;
  const int qblk = id >> 6;
  const int bb = bh >> 4, hh = bh & 15;
  const int q0 = qblk * 128 + w * 32;

  const short* Qp = Qb + ((size_t)bh * 2048 + q0) * 32;
  const short* Kp = Kb + (size_t)bh * 2048 * 32;
  const short* Vp = Vtb + (size_t)bh * 32 * 2048;

  short8 qfA = *(const short8*)(Qp + l15 * 32 + g * 8);
  short8 qfB = *(const short8*)(Qp + (16 + l15) * 32 + g * 8);

  const int kbase = 8 * (l15 >> 2) + (l15 & 3);
  const int koff = (w & 1) * 4 + (w >> 1) * 32;
  const int vrow = (w >> 1) * 16;
  const int vcol = (w & 1) * 32;
  const short* Ksrc0 = Kp + (size_t)(kbase + koff) * 32 + g * 8;
  const short* Vsrc0 = Vp + (size_t)(l15 + vrow) * 2048 + vcol + g * 8;

  f32x4 zf = {0.f, 0.f, 0.f, 0.f};
  f32x4 o_loA = zf, o_hiA = zf, o_loB = zf, o_hiB = zf;
  f32x4 accLA = zf, accLB = zf;
  u32x4 ones_u = {0x3F803F80u, 0x3F803F80u, 0x3F803F80u, 0x3F803F80u};
  const short8 ones = __builtin_bit_cast(short8, ones_u);

#define STAGE(b, t0)                                                        \
  {                                                                         \
    __builtin_amdgcn_global_load_lds((gu32*)(Ksrc0 + (size_t)(t0) * 32),    \
                                     (lu32*)&KV[b][0][w * 512], 16, 0, 0);  \
    __builtin_amdgcn_global_load_lds((gu32*)(Vsrc0 + (t0)),                 \
                                     (lu32*)&KV[b][1][w * 512], 16, 0, 0);  \
  }

#define BODY(b)                                                       \
  {                                                                   \
    short8 k0 = *(const short8*)(&KV[b][0][0 * 512 + lane * 8]);      \
    short8 k1 = *(const short8*)(&KV[b][0][1 * 512 + lane * 8]);      \
    short8 k2 = *(const short8*)(&KV[b][0][2 * 512 + lane * 8]);      \
    short8 k3 = *(const short8*)(&KV[b][0][3 * 512 + lane * 8]);      \
    short8 vlo0 = *(const short8*)(&KV[b][1][0 * 512 + lane * 8]);    \
    short8 vlo1 = *(const short8*)(&KV[b][1][1 * 512 + lane * 8]);    \
    short8 vhi0 = *(const short8*)(&KV[b][1][2 * 512 + lane * 8]);    \
    short8 vhi1 = *(const short8*)(&KV[b][1][3 * 512 + lane * 8]);    \
    short8 pfA0, pfA1, pfB0, pfB1;                                    \
    qk_half(k0, k1, k2, k3, qfA, zf, pfA0, pfA1);                     \
    qk_half(k0, k1, k2, k3, qfB, zf, pfB0, pfB1);                     \
    __builtin_amdgcn_s_setprio(1);                                    \
    accLA = MFMA16(pfA0, ones, accLA);                                \
    accLA = MFMA16(pfA1, ones, accLA);                                \
    accLB = MFMA16(pfB0, ones, accLB);                                \
    accLB = MFMA16(pfB1, ones, accLB);                                \
    o_loA = MFMA16(pfA0, vlo0, o_loA);                                \
    o_loA = MFMA16(pfA1, vlo1, o_loA);                                \
    o_hiA = MFMA16(pfA0, vhi0, o_hiA);                                \
    o_hiA = MFMA16(pfA1, vhi1, o_hiA);                                \
    o_loB = MFMA16(pfB0, vlo0, o_loB);                                \
    o_loB = MFMA16(pfB1, vlo1, o_loB);                                \
    o_hiB = MFMA16(pfB0, vhi0, o_hiB);                                \
    o_hiB = MFMA16(pfB1, vhi1, o_hiB);                                \
    __builtin_amdgcn_s_setprio(0);                                    \
  }

  STAGE(0, 0);
  __syncthreads();
  for (int t0 = 0; t0 < 2048; t0 += 128) {
    STAGE(1, t0 + 64);
    BODY(0);
    __syncthreads();
    if (t0 + 128 < 2048) {
      STAGE(0, t0 + 128);
    }
    BODY(1);
    __syncthreads();
  }
#undef STAGE
#undef BODY

#pragma unroll
  for (int i = 0; i < 4; ++i) {
    float invA = 1.0f / accLA[i];
    float invB = 1.0f / accLB[i];
    int ssA = q0 + 4 * g + i;
    size_t baseA = ((size_t)bb * 2048 + ssA) * 512 + hh * 32;
    X[baseA + l15] = f2b(o_loA[i] * invA);
    X[baseA + 16 + l15] = f2b(o_hiA[i] * invA);
    size_t baseB = baseA + (size_t)16 * 512;
    X[baseB + l15] = f2b(o_loB[i] * invB);
    X[baseB + 16 + l15] = f2b(o_hiB[i] * invB);
  }
}

// ===================== launcher =====================
extern "C" void kernel_launch(void* const* d_in, const int* in_sizes, int n_in,
                              void* d_out, int out_size, void* d_ws, size_t ws_size,
                              hipStream_t stream) {
  const float* q = (const float*)d_in[0];
  const float* k = (const float*)d_in[1];
  const float* v = (const float*)d_in[2];
  const float* Wq = (const float*)d_in[3];
  const float* Wk = (const float*)d_in[4];
  const float* Wv = (const float*)d_in[5];
  const float* Wo = (const float*)d_in[6];

  char* ws = (char*)d_ws;
  const size_t MB = 1u << 20;
  short* WqT = (short*)(ws + 0 * MB);   // [512][1024] bf16  } contiguous =
  short* WkT = (short*)(ws + 1 * MB);   // [512][1024]       } BTall[1536][1024]
  short* WvT = (short*)(ws + 2 * MB);   // [512][1024]       }
  short* WoT = (short*)(ws + 3 * MB);   // [1024][512] bf16
  short* Qb  = (short*)(ws + 4 * MB);   // [64][2048][32] bf16 (8 MiB)
  short* Kb  = (short*)(ws + 12 * MB);  // [64][2048][32]
  short* Vtb = (short*)(ws + 20 * MB);  // [64][32][2048]
  short* Xb  = (short*)(ws + 28 * MB);  // [8192][512]

  prep_weights<<<8192, 256, 0, stream>>>(Wq, Wk, Wv, Wo, WqT, WkT, WvT, WoT);
  proj_gemm<<<768, 1024, 0, stream>>>(q, k, v, WqT, Qb, Kb, Vtb);
  attn<<<1024, 256, 0, stream>>>(Qb, Kb, Vtb, Xb);
  out_gemm<<<512, 256, 0, stream>>>(Xb, WoT, (float*)d_out);
}

// Round 20
// 119.265 us; speedup vs baseline: 1.1572x; 1.1572x over previous
//
#include <hip/hip_runtime.h>
#include <hip/hip_bf16.h>

typedef __attribute__((ext_vector_type(8))) short short8;
typedef __attribute__((ext_vector_type(4))) float f32x4;
typedef __attribute__((ext_vector_type(4))) float fv4;
typedef __attribute__((ext_vector_type(4))) unsigned int u32x4;

#define MFMA16(a, b, c) __builtin_amdgcn_mfma_f32_16x16x32_bf16((a), (b), (c), 0, 0, 0)
#define SBAR() __builtin_amdgcn_sched_barrier(0)
#define RBAR() __builtin_amdgcn_s_barrier()

typedef const __attribute__((address_space(1))) unsigned int gu32;
typedef __attribute__((address_space(3))) unsigned int lu32;

// float -> bf16 RNE (inputs are finite; no NaN handling needed)
__device__ __forceinline__ short f2b(float f) {
  unsigned int x = __builtin_bit_cast(unsigned int, f);
  x += 0x7fffu + ((x >> 16) & 1u);
  return (short)(x >> 16);
}

// packed f32x2 -> bf16x2 (RNE); D.lo = S0, D.hi = S1
__device__ __forceinline__ unsigned int cvtpk(float lo, float hi) {
  unsigned int r;
  asm("v_cvt_pk_bf16_f32 %0, %1, %2" : "=v"(r) : "v"(lo), "v"(hi));
  return r;
}

// hardware 2^x as a compiler-known instruction (TRANS hazards handled)
#define hexp2(x) __builtin_amdgcn_exp2f(x)

// ===================== weight prep =====================
// BTall = [WqT|WkT|WvT] contiguous [1536][1024] bf16; Wq pre-scaled by
// d_model^-0.5 * log2(e). WoT: [1024][512] bf16.
__global__ void prep_weights(const float* __restrict__ Wq, const float* __restrict__ Wk,
                             const float* __restrict__ Wv, const float* __restrict__ Wo,
                             short* __restrict__ WqT, short* __restrict__ WkT,
                             short* __restrict__ WvT, short* __restrict__ WoT) {
  const float SC2 = 0.045084220027780106f;  // (1/32) * log2(e)
  int idx = blockIdx.x * 256 + threadIdx.x;
  if (idx < 3 * 512 * 1024) {
    int wsel = idx >> 19;
    int rem = idx & ((1 << 19) - 1);
    int n = rem >> 10;
    int d = rem & 1023;
    const float* W = (wsel == 0) ? Wq : ((wsel == 1) ? Wk : Wv);
    short* WT = (wsel == 0) ? WqT : ((wsel == 1) ? WkT : WvT);
    float v = W[(n >> 5) * (1024 * 32) + d * 32 + (n & 31)];
    if (wsel == 0) v *= SC2;
    WT[n * 1024 + d] = f2b(v);
  } else {
    int idx2 = idx - 3 * 512 * 1024;
    int n = idx2 >> 9;
    int kk = idx2 & 511;
    WoT[n * 512 + kk] = f2b(Wo[kk * 1024 + n]);
  }
}

// ===================== fused projection GEMM (best measured: R13) =====================
// C[8192,1536] over q/k/v: 128x128 tile, BK=32, 4 waves (2x2), T4 pipeline:
// per step STAGE(next buf, 6 gl_lds) -> s_waitcnt vmcnt(6) (current buf only,
// prefetch stays in flight) -> raw s_barrier -> COMPUTE -> raw s_barrier.
// A staged as f32 via gl_lds (cvtpk f32->bf16 at fragment read), B bf16.
// Swizzles: A slot u^=(row&7) of 8, B slot u^=((row>>1)&3) of 4, applied to
// pre-swizzled global source AND read address (involution).
// Grid 768 = 64bm x 12bn (bn = zz*4+bnz), id%8==bm%8 XCD-pins A panels.
// NOTE: 9 structural alternatives (swizzle/drain/depth/buffering/tile-size/
// occupancy 13-59%) all measured 73-106us vs this 73us — this shape
// (K=1024, N<=1536) is at the demonstrated plain-HIP envelope (m102 curve).
__global__ __launch_bounds__(256, 3) void proj_gemm(
    const float* __restrict__ q, const float* __restrict__ k, const float* __restrict__ v,
    const short* __restrict__ BTall,
    short* __restrict__ Qb, short* __restrict__ Kb, short* __restrict__ Vtb) {
  __shared__ char smem[49152];  // buf0: A@0(16K) B@16384(8K); buf1: A@24576 B@40960
  const int tid = threadIdx.x;
  const int lane = tid & 63;
  const int w = tid >> 6;
  const int l15 = lane & 15, g = lane >> 4;
  const int wm = (w >> 1) * 64, wn = (w & 1) * 64;
  const int id = blockIdx.x;
  const int bm = id & 63;
  const int bn = id >> 6;          // 0..11
  const int bm0 = bm * 128;

  const int zz = bn >> 2;          // 0:q 1:k 2:v
  const int bnz = bn & 3;          // n-block within this input's 512 cols
  const float* Az = (zz == 0) ? q : ((zz == 1) ? k : v);
  const short* BT = BTall + (size_t)zz * 512 * 1024;
  const int bn0z = bnz * 128;

  // A staging: 4 instr/wave, rows 32w+8i+(lane>>3), slot u=lane&7 (16B of 8)
  const int ar = (lane >> 3);
  const int au = lane & 7;
  // B staging: 2 instr/wave, rows 32w+16i+(lane>>2), slot u=lane&3 (16B of 4)
  const int br = (lane >> 2);
  const int bu = lane & 3;

  f32x4 zf = {0.f, 0.f, 0.f, 0.f};
  f32x4 acc[4][4];
#pragma unroll
  for (int a = 0; a < 4; ++a)
#pragma unroll
    for (int bq = 0; bq < 4; ++bq) acc[a][bq] = zf;

#define STAGE(base, k0)                                                        \
  {                                                                            \
    _Pragma("unroll") for (int i = 0; i < 4; ++i) {                            \
      int row = 32 * w + 8 * i + ar;                                           \
      __builtin_amdgcn_global_load_lds(                                        \
          (gu32*)(Az + (size_t)(bm0 + row) * 1024 + (k0) + 4 * (au ^ (row & 7))), \
          (lu32*)(smem + (base) + w * 4096 + i * 1024), 16, 0, 0);             \
    }                                                                          \
    _Pragma("unroll") for (int i = 0; i < 2; ++i) {                            \
      int row = 32 * w + 16 * i + br;                                          \
      __builtin_amdgcn_global_load_lds(                                        \
          (gu32*)(BT + (size_t)(bn0z + row) * 1024 + (k0) +                    \
                  8 * (bu ^ ((row >> 1) & 3))),                                \
          (lu32*)(smem + (base) + 16384 + w * 2048 + i * 1024), 16, 0, 0);     \
    }                                                                          \
  }

#define COMPUTE(base)                                                          \
  {                                                                            \
    short8 af[4], bfr[4];                                                      \
    _Pragma("unroll") for (int mf = 0; mf < 4; ++mf) {                         \
      int row = wm + mf * 16 + l15;                                            \
      fv4 a0 = *(const fv4*)(smem + (base) + row * 128 +                       \
                             (((2 * g) ^ (row & 7)) * 16));                    \
      fv4 a1 = *(const fv4*)(smem + (base) + row * 128 +                       \
                             (((2 * g + 1) ^ (row & 7)) * 16));                \
      u32x4 wv;                                                                \
      wv[0] = cvtpk(a0[0], a0[1]);                                             \
      wv[1] = cvtpk(a0[2], a0[3]);                                             \
      wv[2] = cvtpk(a1[0], a1[1]);                                             \
      wv[3] = cvtpk(a1[2], a1[3]);                                             \
      af[mf] = __builtin_bit_cast(short8, wv);                                 \
    }                                                                          \
    _Pragma("unroll") for (int nf = 0; nf < 4; ++nf) {                         \
      int row = wn + nf * 16 + l15;                                            \
      bfr[nf] = *(const short8*)(smem + (base) + 16384 + row * 64 +            \
                                 ((g ^ ((row >> 1) & 3)) * 16));               \
    }                                                                          \
    _Pragma("unroll") for (int mf = 0; mf < 4; ++mf)                           \
        _Pragma("unroll") for (int nf = 0; nf < 4; ++nf)                       \
            acc[mf][nf] = MFMA16(af[mf], bfr[nf], acc[mf][nf]);                \
  }

  STAGE(0, 0);
  for (int k0 = 0; k0 < 1024; k0 += 32) {
    const int cur = (k0 >> 5) & 1;
    const int cbase = cur * 24576;
    const int nbase = (cur ^ 1) * 24576;
    if (k0 + 32 < 1024) {
      STAGE(nbase, k0 + 32);
      asm volatile("s_waitcnt vmcnt(6)" ::: "memory");
    } else {
      asm volatile("s_waitcnt vmcnt(0)" ::: "memory");
    }
    RBAR();  // all waves' current-buf chunks landed
    SBAR();
    COMPUTE(cbase);
    RBAR();  // all waves done reading before next stage overwrites
  }
#undef STAGE
#undef COMPUTE

#pragma unroll
  for (int mf = 0; mf < 4; ++mf)
#pragma unroll
    for (int nf = 0; nf < 4; ++nf)
#pragma unroll
      for (int i = 0; i < 4; ++i) {
        int row = bm0 + wm + mf * 16 + g * 4 + i;  // m index (b*2048+s)
        int col = bn0z + wn + nf * 16 + l15;       // n within this input's 512
        int bb = row >> 11, ss = row & 2047;
        int hh = col >> 5, ee = col & 31;
        short val = f2b(acc[mf][nf][i]);
        if (zz == 2)
          Vtb[((size_t)(bb * 16 + hh) * 32 + ee) * 2048 + ss] = val;
        else if (zz == 1)
          Kb[((size_t)(bb * 16 + hh) * 2048 + ss) * 32 + ee] = val;
        else
          Qb[((size_t)(bb * 16 + hh) * 2048 + ss) * 32 + ee] = val;
      }
}

// ===================== output GEMM (T4 pipeline) =====================
// C[8192,1024] = X[8192,512] * WoT[1024,512]^T, both bf16. BK=32, 16 steps.
// Same counted-vmcnt structure, 4 gl_lds/step -> vmcnt(4). Grid 512 = 256x2.
__global__ __launch_bounds__(256, 2) void out_gemm(const short* __restrict__ X,
                                                   const short* __restrict__ WoT,
                                                   float* __restrict__ out) {
  __shared__ char smem[32768];  // buf: A 8K + B 8K; bufs @0, @16384
  const int tid = threadIdx.x;
  const int lane = tid & 63;
  const int w = tid >> 6;
  const int l15 = lane & 15, g = lane >> 4;
  const int wm = (w >> 1) * 64, wn = (w & 1) * 64;
  const int id = blockIdx.x;
  const int bm0 = (id & 63) * 128, bn0 = (id >> 6) * 128;

  const int br = (lane >> 2);
  const int bu = lane & 3;

  f32x4 zf = {0.f, 0.f, 0.f, 0.f};
  f32x4 acc[4][4];
#pragma unroll
  for (int a = 0; a < 4; ++a)
#pragma unroll
    for (int bq = 0; bq < 4; ++bq) acc[a][bq] = zf;

#define STAGE(base, k0)                                                        \
  {                                                                            \
    _Pragma("unroll") for (int i = 0; i < 2; ++i) {                            \
      int row = 32 * w + 16 * i + br;                                          \
      __builtin_amdgcn_global_load_lds(                                        \
          (gu32*)(X + (size_t)(bm0 + row) * 512 + (k0) +                       \
                  8 * (bu ^ ((row >> 1) & 3))),                                \
          (lu32*)(smem + (base) + w * 2048 + i * 1024), 16, 0, 0);             \
      __builtin_amdgcn_global_load_lds(                                        \
          (gu32*)(WoT + (size_t)(bn0 + row) * 512 + (k0) +                     \
                  8 * (bu ^ ((row >> 1) & 3))),                                \
          (lu32*)(smem + (base) + 8192 + w * 2048 + i * 1024), 16, 0, 0);      \
    }                                                                          \
  }

#define COMPUTE(base)                                                          \
  {                                                                            \
    short8 af[4], bfr[4];                                                      \
    _Pragma("unroll") for (int mf = 0; mf < 4; ++mf) {                         \
      int row = wm + mf * 16 + l15;                                            \
      af[mf] = *(const short8*)(smem + (base) + row * 64 +                     \
                                ((g ^ ((row >> 1) & 3)) * 16));                \
    }                                                                          \
    _Pragma("unroll") for (int nf = 0; nf < 4; ++nf) {                         \
      int row = wn + nf * 16 + l15;                                            \
      bfr[nf] = *(const short8*)(smem + (base) + 8192 + row * 64 +             \
                                 ((g ^ ((row >> 1) & 3)) * 16));               \
    }                                                                          \
    _Pragma("unroll") for (int mf = 0; mf < 4; ++mf)                           \
        _Pragma("unroll") for (int nf = 0; nf < 4; ++nf)                       \
            acc[mf][nf] = MFMA16(af[mf], bfr[nf], acc[mf][nf]);                \
  }

  STAGE(0, 0);
  for (int k0 = 0; k0 < 512; k0 += 32) {
    const int cur = (k0 >> 5) & 1;
    const int cbase = cur * 16384;
    const int nbase = (cur ^ 1) * 16384;
    if (k0 + 32 < 512) {
      STAGE(nbase, k0 + 32);
      asm volatile("s_waitcnt vmcnt(4)" ::: "memory");
    } else {
      asm volatile("s_waitcnt vmcnt(0)" ::: "memory");
    }
    RBAR();
    SBAR();
    COMPUTE(cbase);
    RBAR();
  }
#undef STAGE
#undef COMPUTE

#pragma unroll
  for (int mf = 0; mf < 4; ++mf)
#pragma unroll
    for (int nf = 0; nf < 4; ++nf)
#pragma unroll
      for (int i = 0; i < 4; ++i) {
        int row = bm0 + wm + mf * 16 + g * 4 + i;
        int col = bn0 + wn + nf * 16 + l15;
        out[(size_t)row * 1024 + col] = acc[mf][nf][i];
      }
}

// ===================== fused flash attention (best measured: R9) =====================
// Swapped QK^T (mfma(K,Q)) + permuted K-row loads: softmax fully lane-local.
// No online max (base-2 logits: exp2 cannot overflow f32). 32 Q rows/wave.
// Block = 4 waves share one K/V stream: per 64-t body the block stages
// K(4KB)+V(4KB) into LDS once via 16B gl_lds (lane-linear dest, permutation
// folded into per-lane global source), double-buffered, waves ds_read_b128
// stride-1 conflict-free. Denominator via ones-MFMA. Head-pinned XCD grid.
__device__ __forceinline__ void qk_half(short8 k0, short8 k1, short8 k2, short8 k3,
                                        short8 qf, const f32x4& zf,
                                        short8& pf0, short8& pf1) {
  f32x4 s0 = MFMA16(k0, qf, zf);
  f32x4 s1 = MFMA16(k1, qf, zf);
  f32x4 s2 = MFMA16(k2, qf, zf);
  f32x4 s3 = MFMA16(k3, qf, zf);
#pragma unroll
  for (int i = 0; i < 4; ++i) {
    s0[i] = hexp2(s0[i]);
    s1[i] = hexp2(s1[i]);
    s2[i] = hexp2(s2[i]);
    s3[i] = hexp2(s3[i]);
  }
  u32x4 w0, w1;
  w0[0] = cvtpk(s0[0], s0[1]);
  w0[1] = cvtpk(s0[2], s0[3]);
  w0[2] = cvtpk(s1[0], s1[1]);
  w0[3] = cvtpk(s1[2], s1[3]);
  w1[0] = cvtpk(s2[0], s2[1]);
  w1[1] = cvtpk(s2[2], s2[3]);
  w1[2] = cvtpk(s3[0], s3[1]);
  w1[3] = cvtpk(s3[2], s3[3]);
  pf0 = __builtin_bit_cast(short8, w0);
  pf1 = __builtin_bit_cast(short8, w1);
}

__global__ __launch_bounds__(256, 4) void attn(const short* __restrict__ Qb,
                                               const short* __restrict__ Kb,
                                               const short* __restrict__ Vtb,
                                               short* __restrict__ X) {
  __shared__ short KV[2][2][2048];
  const int tid = threadIdx.x;
  const int lane = tid & 63;
  const int w = tid >> 6;
  const int l15 = lane & 15, g = lane >> 4;
  const int id = blockIdx.x;       // id = qblk*64 + bh  ->  id%8 == bh%8
  const int bh = id & 63;
  const int qblk = id >> 6;        // 0..15
  const int bb = bh >> 4, hh = bh & 15;
  const int q0 = qblk * 128 + w * 32;

  const short* Qp = Qb + ((size_t)bh * 2048 + q0) * 32;
  const short* Kp = Kb + (size_t)bh * 2048 * 32;
  const short* Vp = Vtb + (size_t)bh * 32 * 2048;

  short8 qfA = *(const short8*)(Qp + l15 * 32 + g * 8);
  short8 qfB = *(const short8*)(Qp + (16 + l15) * 32 + g * 8);

  const int kbase = 8 * (l15 >> 2) + (l15 & 3);
  const int koff = (w & 1) * 4 + (w >> 1) * 32;   // chunk w: {0,4,32,36}
  const int vrow = (w >> 1) * 16;
  const int vcol = (w & 1) * 32;
  const short* Ksrc0 = Kp + (size_t)(kbase + koff) * 32 + g * 8;
  const short* Vsrc0 = Vp + (size_t)(l15 + vrow) * 2048 + vcol + g * 8;

  f32x4 zf = {0.f, 0.f, 0.f, 0.f};
  f32x4 o_loA = zf, o_hiA = zf, o_loB = zf, o_hiB = zf;
  f32x4 accLA = zf, accLB = zf;
  u32x4 ones_u = {0x3F803F80u, 0x3F803F80u, 0x3F803F80u, 0x3F803F80u};
  const short8 ones = __builtin_bit_cast(short8, ones_u);

#define STAGE(b, t0)                                                        \
  {                                                                         \
    __builtin_amdgcn_global_load_lds((gu32*)(Ksrc0 + (size_t)(t0) * 32),    \
                                     (lu32*)&KV[b][0][w * 512], 16, 0, 0);  \
    __builtin_amdgcn_global_load_lds((gu32*)(Vsrc0 + (t0)),                 \
                                     (lu32*)&KV[b][1][w * 512], 16, 0, 0);  \
  }

#define BODY(b)                                                       \
  {                                                                   \
    short8 k0 = *(const short8*)(&KV[b][0][0 * 512 + lane * 8]);      \
    short8 k1 = *(const short8*)(&KV[b][0][1 * 512 + lane * 8]);      \
    short8 k2 = *(const short8*)(&KV[b][0][2 * 512 + lane * 8]);      \
    short8 k3 = *(const short8*)(&KV[b][0][3 * 512 + lane * 8]);      \
    short8 vlo0 = *(const short8*)(&KV[b][1][0 * 512 + lane * 8]);    \
    short8 vlo1 = *(const short8*)(&KV[b][1][1 * 512 + lane * 8]);    \
    short8 vhi0 = *(const short8*)(&KV[b][1][2 * 512 + lane * 8]);    \
    short8 vhi1 = *(const short8*)(&KV[b][1][3 * 512 + lane * 8]);    \
    short8 pfA0, pfA1, pfB0, pfB1;                                    \
    qk_half(k0, k1, k2, k3, qfA, zf, pfA0, pfA1);                     \
    qk_half(k0, k1, k2, k3, qfB, zf, pfB0, pfB1);                     \
    __builtin_amdgcn_s_setprio(1);                                    \
    accLA = MFMA16(pfA0, ones, accLA);                                \
    accLA = MFMA16(pfA1, ones, accLA);                                \
    accLB = MFMA16(pfB0, ones, accLB);                                \
    accLB = MFMA16(pfB1, ones, accLB);                                \
    o_loA = MFMA16(pfA0, vlo0, o_loA);                                \
    o_loA = MFMA16(pfA1, vlo1, o_loA);                                \
    o_hiA = MFMA16(pfA0, vhi0, o_hiA);                                \
    o_hiA = MFMA16(pfA1, vhi1, o_hiA);                                \
    o_loB = MFMA16(pfB0, vlo0, o_loB);                                \
    o_loB = MFMA16(pfB1, vlo1, o_loB);                                \
    o_hiB = MFMA16(pfB0, vhi0, o_hiB);                                \
    o_hiB = MFMA16(pfB1, vhi1, o_hiB);                                \
    __builtin_amdgcn_s_setprio(0);                                    \
  }

  STAGE(0, 0);
  __syncthreads();
  for (int t0 = 0; t0 < 2048; t0 += 128) {
    STAGE(1, t0 + 64);
    BODY(0);
    __syncthreads();
    if (t0 + 128 < 2048) {
      STAGE(0, t0 + 128);
    }
    BODY(1);
    __syncthreads();
  }
#undef STAGE
#undef BODY

#pragma unroll
  for (int i = 0; i < 4; ++i) {
    float invA = 1.0f / accLA[i];
    float invB = 1.0f / accLB[i];
    int ssA = q0 + 4 * g + i;
    size_t baseA = ((size_t)bb * 2048 + ssA) * 512 + hh * 32;
    X[baseA + l15] = f2b(o_loA[i] * invA);
    X[baseA + 16 + l15] = f2b(o_hiA[i] * invA);
    size_t baseB = baseA + (size_t)16 * 512;
    X[baseB + l15] = f2b(o_loB[i] * invB);
    X[baseB + 16 + l15] = f2b(o_hiB[i] * invB);
  }
}

// ===================== launcher =====================
extern "C" void kernel_launch(void* const* d_in, const int* in_sizes, int n_in,
                              void* d_out, int out_size, void* d_ws, size_t ws_size,
                              hipStream_t stream) {
  const float* q = (const float*)d_in[0];
  const float* k = (const float*)d_in[1];
  const float* v = (const float*)d_in[2];
  const float* Wq = (const float*)d_in[3];
  const float* Wk = (const float*)d_in[4];
  const float* Wv = (const float*)d_in[5];
  const float* Wo = (const float*)d_in[6];

  char* ws = (char*)d_ws;
  const size_t MB = 1u << 20;
  short* WqT = (short*)(ws + 0 * MB);   // [512][1024] bf16  } contiguous =
  short* WkT = (short*)(ws + 1 * MB);   // [512][1024]       } BTall[1536][1024]
  short* WvT = (short*)(ws + 2 * MB);   // [512][1024]       }
  short* WoT = (short*)(ws + 3 * MB);   // [1024][512] bf16
  short* Qb  = (short*)(ws + 4 * MB);   // [64][2048][32] bf16 (8 MiB)
  short* Kb  = (short*)(ws + 12 * MB);  // [64][2048][32]
  short* Vtb = (short*)(ws + 20 * MB);  // [64][32][2048]
  short* Xb  = (short*)(ws + 28 * MB);  // [8192][512]

  prep_weights<<<8192, 256, 0, stream>>>(Wq, Wk, Wv, Wo, WqT, WkT, WvT, WoT);
  proj_gemm<<<768, 256, 0, stream>>>(q, k, v, WqT, Qb, Kb, Vtb);
  attn<<<1024, 256, 0, stream>>>(Qb, Kb, Vtb, Xb);
  out_gemm<<<512, 256, 0, stream>>>(Xb, WoT, (float*)d_out);
}